// Round 21
// baseline (38.402 us; speedup 1.0000x reference)
//
#include <hip/hip_runtime.h>
#include <hip/hip_bf16.h>

#define NN 512
#define NH 64
#define MAXD 96            // list capacity (deg mean 32, sigma 5.5 -> +11 sigma)
#define ZBYTE (511 * 128)  // sentinel -> byte row offset of row 511 (always zeroed)

typedef _Float16 h4 __attribute__((ext_vector_type(4)));
typedef _Float16 h8 __attribute__((ext_vector_type(8)));
typedef float f32x4 __attribute__((ext_vector_type(4)));

// ---------------- ws layout (bytes) ----------------
// nbr   : NN*MAXD*4 = 196608 @ 0       entries = r*128 (byte row offset), sentinel ZBYTE
// g16   : NN*NH*2   = 65536  @ 196608  fp16 z@W1 tile (unscaled)
// pcntC : NN*NN     = 262144 @ 262144  u8 pcntC[c][t] = #{r in nbr(c): r < t}
// ph    : NN*NN*4   = 1048576@ 524288  f32 ph[i][k] = deg_k*hid[i][k], valid k<i
// total = 1572864

// K1: 512 blocks x 512 thr. Every block: build list + pcntC row for column
// c = b (adj symmetric). Blocks 0..255: one 32x32 tile of out = z@z^T via
// MFMA fp16 (verified layout, R18). Blocks 256..287: one 16-row slab of
// g16 = fp16(z @ W1[:256]) via MFMA (W1 staged transposed fp16 in LDS).
__global__ __launch_bounds__(512) void build_gemms(const float* __restrict__ adj,
                                                   const float* __restrict__ z,
                                                   const float* __restrict__ W1,
                                                   unsigned* __restrict__ nbr,
                                                   unsigned char* __restrict__ pcntC,
                                                   _Float16* __restrict__ g16,
                                                   float* __restrict__ out) {
    __shared__ __align__(16) char smem[42240];   // union across phases
    const int b = (int)blockIdx.x;
    const int tid = (int)threadIdx.x;
    const int lane = tid & 63, w = tid >> 6;

    {   // ---- phase A: build list + pcntC row for column c = b ----
        int* wcnt = (int*)smem;
        const int c = b;
        bool f = (adj[c * NN + tid] != 0.0f);
        unsigned long long m = __ballot(f);
        int before = __popcll(m & ((1ull << lane) - 1ull));
        if (lane == 0) wcnt[w] = __popcll(m);
        __syncthreads();
        int pre = 0, total = 0;
        #pragma unroll
        for (int j = 0; j < 8; ++j) {
            int x = wcnt[j];
            pre += (j < w) ? x : 0;
            total += x;
        }
        pcntC[c * NN + tid] = (unsigned char)(pre + before);  // coalesced row write
        unsigned* row = nbr + c * MAXD;
        int pos = pre + before;
        if (f && pos < MAXD) row[pos] = (unsigned)(tid << 7);
        int m2 = total < MAXD ? total : MAXD;
        for (int j = m2 + tid; j < MAXD; j += 512) row[j] = ZBYTE;
        __syncthreads();
    }

    if (b < 256) {
        // ---- zz^T 32x32 tile (bi, bj) via MFMA fp16 ----
        const int bi = b >> 4, bj = b & 15;
        _Float16 (*As16)[264] = (_Float16(*)[264])smem;            // 32 x 264 fp16
        _Float16 (*Bs16)[264] = (_Float16(*)[264])(smem + 16896);  // 32 x 264 fp16
        #pragma unroll
        for (int l = 0; l < 4; ++l) {
            int idx = tid + (l << 9);             // 0..2047
            int r = idx >> 6, c4 = (idx & 63) << 2;
            float4 a  = *(const float4*)&z[(bi * 32 + r) * 256 + c4];
            float4 bb = *(const float4*)&z[(bj * 32 + r) * 256 + c4];
            h4 ah = {(_Float16)a.x,  (_Float16)a.y,  (_Float16)a.z,  (_Float16)a.w};
            h4 bh = {(_Float16)bb.x, (_Float16)bb.y, (_Float16)bb.z, (_Float16)bb.w};
            *(h4*)&As16[r][c4] = ah;
            *(h4*)&Bs16[r][c4] = bh;
        }
        __syncthreads();
        if (tid < 256) {                          // waves 0..3, one 16x16 subtile each
            const int mi = w & 1, ni = w >> 1;
            const int r16 = lane & 15, kg = (lane >> 4) << 3;
            f32x4 acc = {};
            #pragma unroll
            for (int kk = 0; kk < 256; kk += 32) {
                h8 av = *(const h8*)&As16[mi * 16 + r16][kk + kg];
                h8 bv = *(const h8*)&Bs16[ni * 16 + r16][kk + kg];
                acc = __builtin_amdgcn_mfma_f32_16x16x32_f16(av, bv, acc, 0, 0, 0);
            }
            // C/D layout: col = lane&15, row = (lane>>4)*4 + reg  (HW-verified R18)
            const int orow = bi * 32 + mi * 16 + ((lane >> 4) << 2);
            const int ocol = bj * 32 + ni * 16 + (lane & 15);
            #pragma unroll
            for (int j = 0; j < 4; ++j)
                out[(orow + j) * NN + ocol] = acc[j];
        }
    } else if (b < 288) {
        // ---- g16 = fp16(z @ W1[:256]) via MFMA, 16-row slab ----
        const int bi = b - 256;                    // slab of rows [16*bi, 16*bi+16)
        _Float16 (*BsT)[264] = (_Float16(*)[264])smem;             // 64 x 264 (W1^T)
        _Float16 (*Asg)[264] = (_Float16(*)[264])(smem + 33792);   // 16 x 264 (z rows)
        #pragma unroll
        for (int it = 0; it < 8; ++it) {           // stage W1^T: 256x16 float4 reads
            int idx = tid + (it << 9);             // 0..4095
            int k = idx >> 4, n4 = (idx & 15) << 2;
            float4 wv = *(const float4*)&W1[k * 64 + n4];
            BsT[n4 + 0][k] = (_Float16)wv.x;
            BsT[n4 + 1][k] = (_Float16)wv.y;
            BsT[n4 + 2][k] = (_Float16)wv.z;
            BsT[n4 + 3][k] = (_Float16)wv.w;
        }
        #pragma unroll
        for (int it = 0; it < 2; ++it) {           // stage 16 z rows
            int idx = tid + (it << 9);             // 0..1023
            int r = idx >> 6, c4 = (idx & 63) << 2;
            float4 a = *(const float4*)&z[(bi * 16 + r) * 256 + c4];
            h4 ah = {(_Float16)a.x, (_Float16)a.y, (_Float16)a.z, (_Float16)a.w};
            *(h4*)&Asg[r][c4] = ah;
        }
        __syncthreads();
        if (tid < 256) {                           // wave w: col-tile n16 = 16*w
            const int n16 = w << 4;
            const int r16 = lane & 15, kg = (lane >> 4) << 3;
            f32x4 acc = {};
            #pragma unroll
            for (int kk = 0; kk < 256; kk += 32) {
                h8 av = *(const h8*)&Asg[r16][kk + kg];
                h8 bv = *(const h8*)&BsT[n16 + r16][kk + kg];
                acc = __builtin_amdgcn_mfma_f32_16x16x32_f16(av, bv, acc, 0, 0, 0);
            }
            const int orow = bi * 16 + ((lane >> 4) << 2);
            const int ocol = n16 + (lane & 15);
            #pragma unroll
            for (int j = 0; j < 4; ++j)
                g16[(orow + j) * NH + ocol] = (_Float16)acc[j];
        }
    }
}

// K2: visit-balanced hid, b128 inner loop. Grid (3, 512): block (c, b)
// handles i = 511-b, k in [c*i/3, (c+1)*i/3). Each 8-LANE GROUP owns one k
// (8 k's per wave): lane reads 16B of the 128B row via ds_read_b128 ->
// one wave-instruction covers 32 visits (2x the b64 form). Bank-uniform:
// each row's 8 lanes cover all 32 banks once. deg via one strided byte
// gather pcntC[tid*NN + i]. Stores ph = deg_k*hid.
__global__ __launch_bounds__(1024, 8) void hidk(const unsigned* __restrict__ nbr,
                                                const unsigned char* __restrict__ pcntC,
                                                const _Float16* __restrict__ g16,
                                                const float* __restrict__ W2,
                                                float* __restrict__ ph) {
    __shared__ _Float16 g2[NN * NH];   // 64 KB deg-scaled tile
    __shared__ float degl[NN];
    __shared__ short pcl[NN];
    const int i = 511 - (int)blockIdx.y;   // big i first
    const int c = (int)blockIdx.x;
    const int kc0 = (c * i) / 3, kc1 = ((c + 1) * i) / 3;
    if (kc0 >= kc1) return;
    const int tid = threadIdx.x, lane = tid & 63, w = tid >> 6;

    if (tid < NN) {
        int pc = (int)pcntC[tid * NN + i];           // strided byte gather (once)
        pcl[tid] = (short)pc;
        degl[tid] = (tid < i) ? rsqrtf((float)(pc > 0 ? pc : 1)) : 0.0f;
    }
    __syncthreads();
    {   // stage rows < i scaled; zero rows >= i
        const uint4* s = (const uint4*)g16;
        uint4* d = (uint4*)g2;
        const int ci = i << 3;
        for (int t = tid; t < ci; t += 1024) {
            int l = t >> 3;
            uint4 raw = s[t];
            _Float16 dh = (_Float16)degl[l];
            h4 dv = {dh, dh, dh, dh};
            h4 a0 = ((h4*)&raw)[0] * dv;
            h4 a1 = ((h4*)&raw)[1] * dv;
            uint4 o;
            ((h4*)&o)[0] = a0; ((h4*)&o)[1] = a1;
            d[t] = o;
        }
        const uint4 zz = {0u, 0u, 0u, 0u};
        for (int t = ci + tid; t < NN * 8; t += 1024) d[t] = zz;
    }
    __syncthreads();

    const int e8 = lane >> 3;                // 8-lane group id 0..7
    const int lofs = (lane & 7) << 4;        // 16B offset within 128B row
    const int h0 = (lane & 7) << 3;          // h-range start for this lane
    const float4 w2a = *(const float4*)&W2[h0];
    const float4 w2b = *(const float4*)&W2[h0 + 4];
    const char* g2b = (const char*)g2;

    for (int k0 = kc0 + (w << 3); k0 < kc1; k0 += 64) {
        const int kq = k0 + e8;
        const int kqc = kq < 511 ? kq : 511;
        int pk = (kq < kc1) ? (int)pcl[kqc] : 0;
        int mx = max(pk, __shfl_xor(pk, 8, 64));
        mx = max(mx, __shfl_xor(mx, 16, 64));
        mx = max(mx, __shfl_xor(mx, 32, 64));
        const int nbu = __builtin_amdgcn_readfirstlane((mx + 3) >> 2);
        const uint4* l4 = (const uint4*)(nbr + kqc * MAXD);
        h8 acc0 = {}, acc1 = {};
        uint4 e0 = l4[0], e1 = l4[1];        // 2-deep rolling prefetch
        for (int g = 0; g < nbu; ++g) {
            uint4 en = l4[g + 2];            // harmless in-row over-read
            acc0 += *(const h8*)(g2b + (e0.x + lofs));
            acc1 += *(const h8*)(g2b + (e0.y + lofs));
            acc0 += *(const h8*)(g2b + (e0.z + lofs));
            acc1 += *(const h8*)(g2b + (e0.w + lofs));
            e0 = e1; e1 = en;
        }
        h8 acc = acc0 + acc1;
        const float dk = degl[kqc];          // 0 for kq >= i
        float val = fmaxf(dk * (float)acc[0], 0.f) * w2a.x
                  + fmaxf(dk * (float)acc[1], 0.f) * w2a.y
                  + fmaxf(dk * (float)acc[2], 0.f) * w2a.z
                  + fmaxf(dk * (float)acc[3], 0.f) * w2a.w
                  + fmaxf(dk * (float)acc[4], 0.f) * w2b.x
                  + fmaxf(dk * (float)acc[5], 0.f) * w2b.y
                  + fmaxf(dk * (float)acc[6], 0.f) * w2b.z
                  + fmaxf(dk * (float)acc[7], 0.f) * w2b.w;
        val += __shfl_xor(val, 1, 64);
        val += __shfl_xor(val, 2, 64);
        val += __shfl_xor(val, 4, 64);
        if ((lane & 7) == 0 && kq < kc1) ph[i * NN + kq] = dk * val;  // deg_k*hid
    }
}

// K3: supplement scatter (R19's best-config form). s[i][j] = 0.5*deg_j*
// sum_{k in nbr(j), k<i} ph[i][k]; out[i][j] += s, out[j][i] += s
// (block i owns row i & col i -> race-free). Over-reads hit phl[r>=i] == 0.
__global__ __launch_bounds__(512) void supp(const unsigned* __restrict__ nbr,
                                            const unsigned char* __restrict__ pcntC,
                                            const float* __restrict__ ph,
                                            float* __restrict__ out) {
    __shared__ float phl[NN];
    const int i = 511 - (int)blockIdx.x;
    if (i < 1) return;
    const int tid = threadIdx.x;
    const int pc = (int)pcntC[tid * NN + i];         // strided byte gather (once)
    phl[tid] = (tid < i) ? ph[i * NN + tid] : 0.0f;  // ph already deg_k-scaled
    __syncthreads();
    if (tid < i) {
        const float d = rsqrtf((float)(pc > 0 ? pc : 1));
        const uint4* l4 = (const uint4*)(nbr + tid * MAXD);
        const int nb = (pc + 3) >> 2;
        float s = 0.f;
        for (int g = 0; g < nb; ++g) {
            uint4 qv = l4[g];   // over-read entries land on phl[r>=i] == 0
            s += phl[qv.x >> 7] + phl[qv.y >> 7] + phl[qv.z >> 7] + phl[qv.w >> 7];
        }
        s *= 0.5f * d;
        out[i * NN + tid] += s;
        out[tid * NN + i] += s;
    }
}

extern "C" void kernel_launch(void* const* d_in, const int* in_sizes, int n_in,
                              void* d_out, int out_size, void* d_ws, size_t ws_size,
                              hipStream_t stream) {
    const float* z   = (const float*)d_in[0];
    const float* adj = (const float*)d_in[1];
    const float* W1  = (const float*)d_in[2];
    const float* W2  = (const float*)d_in[3];
    float* out = (float*)d_out;

    char* wsp = (char*)d_ws;
    unsigned*       nbr   = (unsigned*)      (wsp + 0);
    _Float16*       g16   = (_Float16*)      (wsp + 196608);
    unsigned char*  pcntC = (unsigned char*) (wsp + 262144);
    float*          ph    = (float*)         (wsp + 524288);

    build_gemms<<<NN, 512, 0, stream>>>(adj, z, W1, nbr, pcntC, g16, out);
    hidk<<<dim3(3, NN), 1024, 0, stream>>>(nbr, pcntC, g16, W2, ph);
    supp<<<NN, 512, 0, stream>>>(nbr, pcntC, ph, out);
}

// Round 22
// 36.966 us; speedup vs baseline: 1.0388x; 1.0388x over previous
//
#include <hip/hip_runtime.h>
#include <hip/hip_bf16.h>

#define NN 512
#define NH 64
#define MAXD 96            // list capacity (deg mean 32, sigma 5.5 -> +11 sigma)
#define ZBYTE (511 * 128)  // sentinel -> byte row offset of row 511 (always zeroed)

typedef _Float16 h4 __attribute__((ext_vector_type(4)));
typedef _Float16 h8 __attribute__((ext_vector_type(8)));
typedef float f32x4 __attribute__((ext_vector_type(4)));

// ---------------- ws layout (bytes) ----------------
// nbr   : NN*MAXD*4 = 196608 @ 0       entries = r*128 (byte row offset), sentinel ZBYTE
// g16   : NN*NH*2   = 65536  @ 196608  fp16 z@W1 tile (unscaled)
// pcntC : NN*NN     = 262144 @ 262144  u8 pcntC[c][t] = #{r in nbr(c): r < t}
// ph    : NN*NN*4   = 1048576@ 524288  f32 ph[i][k] = deg_k*hid[i][k], valid k<i
// total = 1572864

// K1: 512 blocks x 512 thr. Every block: build list + pcntC row for column
// c = b (adj symmetric). Blocks 0..255: one 32x32 tile of out = z@z^T via
// MFMA fp16 (verified layout, R18). Blocks 256..287: one 16-row slab of
// g16 = fp16(z @ W1[:256]) via MFMA (W1 staged transposed fp16 in LDS).
__global__ __launch_bounds__(512) void build_gemms(const float* __restrict__ adj,
                                                   const float* __restrict__ z,
                                                   const float* __restrict__ W1,
                                                   unsigned* __restrict__ nbr,
                                                   unsigned char* __restrict__ pcntC,
                                                   _Float16* __restrict__ g16,
                                                   float* __restrict__ out) {
    __shared__ __align__(16) char smem[42240];   // union across phases
    const int b = (int)blockIdx.x;
    const int tid = (int)threadIdx.x;
    const int lane = tid & 63, w = tid >> 6;

    {   // ---- phase A: build list + pcntC row for column c = b ----
        int* wcnt = (int*)smem;
        const int c = b;
        bool f = (adj[c * NN + tid] != 0.0f);
        unsigned long long m = __ballot(f);
        int before = __popcll(m & ((1ull << lane) - 1ull));
        if (lane == 0) wcnt[w] = __popcll(m);
        __syncthreads();
        int pre = 0, total = 0;
        #pragma unroll
        for (int j = 0; j < 8; ++j) {
            int x = wcnt[j];
            pre += (j < w) ? x : 0;
            total += x;
        }
        pcntC[c * NN + tid] = (unsigned char)(pre + before);  // coalesced row write
        unsigned* row = nbr + c * MAXD;
        int pos = pre + before;
        if (f && pos < MAXD) row[pos] = (unsigned)(tid << 7);
        int m2 = total < MAXD ? total : MAXD;
        for (int j = m2 + tid; j < MAXD; j += 512) row[j] = ZBYTE;
        __syncthreads();
    }

    if (b < 256) {
        // ---- zz^T 32x32 tile (bi, bj) via MFMA fp16 ----
        const int bi = b >> 4, bj = b & 15;
        _Float16 (*As16)[264] = (_Float16(*)[264])smem;            // 32 x 264 fp16
        _Float16 (*Bs16)[264] = (_Float16(*)[264])(smem + 16896);  // 32 x 264 fp16
        #pragma unroll
        for (int l = 0; l < 4; ++l) {
            int idx = tid + (l << 9);             // 0..2047
            int r = idx >> 6, c4 = (idx & 63) << 2;
            float4 a  = *(const float4*)&z[(bi * 32 + r) * 256 + c4];
            float4 bb = *(const float4*)&z[(bj * 32 + r) * 256 + c4];
            h4 ah = {(_Float16)a.x,  (_Float16)a.y,  (_Float16)a.z,  (_Float16)a.w};
            h4 bh = {(_Float16)bb.x, (_Float16)bb.y, (_Float16)bb.z, (_Float16)bb.w};
            *(h4*)&As16[r][c4] = ah;
            *(h4*)&Bs16[r][c4] = bh;
        }
        __syncthreads();
        if (tid < 256) {                          // waves 0..3, one 16x16 subtile each
            const int mi = w & 1, ni = w >> 1;
            const int r16 = lane & 15, kg = (lane >> 4) << 3;
            f32x4 acc = {};
            #pragma unroll
            for (int kk = 0; kk < 256; kk += 32) {
                h8 av = *(const h8*)&As16[mi * 16 + r16][kk + kg];
                h8 bv = *(const h8*)&Bs16[ni * 16 + r16][kk + kg];
                acc = __builtin_amdgcn_mfma_f32_16x16x32_f16(av, bv, acc, 0, 0, 0);
            }
            // C/D layout: col = lane&15, row = (lane>>4)*4 + reg  (HW-verified R18)
            const int orow = bi * 32 + mi * 16 + ((lane >> 4) << 2);
            const int ocol = bj * 32 + ni * 16 + (lane & 15);
            #pragma unroll
            for (int j = 0; j < 4; ++j)
                out[(orow + j) * NN + ocol] = acc[j];
        }
    } else if (b < 288) {
        // ---- g16 = fp16(z @ W1[:256]) via MFMA, 16-row slab ----
        const int bi = b - 256;                    // slab of rows [16*bi, 16*bi+16)
        _Float16 (*BsT)[264] = (_Float16(*)[264])smem;             // 64 x 264 (W1^T)
        _Float16 (*Asg)[264] = (_Float16(*)[264])(smem + 33792);   // 16 x 264 (z rows)
        #pragma unroll
        for (int it = 0; it < 8; ++it) {           // stage W1^T: 256x16 float4 reads
            int idx = tid + (it << 9);             // 0..4095
            int k = idx >> 4, n4 = (idx & 15) << 2;
            float4 wv = *(const float4*)&W1[k * 64 + n4];
            BsT[n4 + 0][k] = (_Float16)wv.x;
            BsT[n4 + 1][k] = (_Float16)wv.y;
            BsT[n4 + 2][k] = (_Float16)wv.z;
            BsT[n4 + 3][k] = (_Float16)wv.w;
        }
        #pragma unroll
        for (int it = 0; it < 2; ++it) {           // stage 16 z rows
            int idx = tid + (it << 9);             // 0..1023
            int r = idx >> 6, c4 = (idx & 63) << 2;
            float4 a = *(const float4*)&z[(bi * 16 + r) * 256 + c4];
            h4 ah = {(_Float16)a.x, (_Float16)a.y, (_Float16)a.z, (_Float16)a.w};
            *(h4*)&Asg[r][c4] = ah;
        }
        __syncthreads();
        if (tid < 256) {                           // wave w: col-tile n16 = 16*w
            const int n16 = w << 4;
            const int r16 = lane & 15, kg = (lane >> 4) << 3;
            f32x4 acc = {};
            #pragma unroll
            for (int kk = 0; kk < 256; kk += 32) {
                h8 av = *(const h8*)&Asg[r16][kk + kg];
                h8 bv = *(const h8*)&BsT[n16 + r16][kk + kg];
                acc = __builtin_amdgcn_mfma_f32_16x16x32_f16(av, bv, acc, 0, 0, 0);
            }
            const int orow = bi * 16 + ((lane >> 4) << 2);
            const int ocol = n16 + (lane & 15);
            #pragma unroll
            for (int j = 0; j < 4; ++j)
                g16[(orow + j) * NH + ocol] = (_Float16)acc[j];
        }
    }
}

// K2: visit-balanced hid (measured 5.9us; best config R19). Grid (3, 512):
// block (c, b) handles i = 511-b, k in [c*i/3, (c+1)*i/3). deg via one
// strided byte gather pcntC[tid*NN + i]. g2[l][h] = deg_i[l]*g16[l][h],
// rows >= i zeroed. Quarter q of each wave owns one k; 2-deep rolling
// list prefetch. Stores ph = deg_k*hid.
__global__ __launch_bounds__(1024, 8) void hidk(const unsigned* __restrict__ nbr,
                                                const unsigned char* __restrict__ pcntC,
                                                const _Float16* __restrict__ g16,
                                                const float* __restrict__ W2,
                                                float* __restrict__ ph) {
    __shared__ _Float16 g2[NN * NH];   // 64 KB deg-scaled tile
    __shared__ float degl[NN];
    __shared__ short pcl[NN];
    const int i = 511 - (int)blockIdx.y;   // big i first
    const int c = (int)blockIdx.x;
    const int kc0 = (c * i) / 3, kc1 = ((c + 1) * i) / 3;
    if (kc0 >= kc1) return;
    const int tid = threadIdx.x, lane = tid & 63, w = tid >> 6;

    if (tid < NN) {
        int pc = (int)pcntC[tid * NN + i];           // strided byte gather (once)
        pcl[tid] = (short)pc;
        degl[tid] = (tid < i) ? rsqrtf((float)(pc > 0 ? pc : 1)) : 0.0f;
    }
    __syncthreads();
    {   // stage rows < i scaled; zero rows >= i
        const uint4* s = (const uint4*)g16;
        uint4* d = (uint4*)g2;
        const int ci = i << 3;
        for (int t = tid; t < ci; t += 1024) {
            int l = t >> 3;
            uint4 raw = s[t];
            _Float16 dh = (_Float16)degl[l];
            h4 dv = {dh, dh, dh, dh};
            h4 a0 = ((h4*)&raw)[0] * dv;
            h4 a1 = ((h4*)&raw)[1] * dv;
            uint4 o;
            ((h4*)&o)[0] = a0; ((h4*)&o)[1] = a1;
            d[t] = o;
        }
        const uint4 zz = {0u, 0u, 0u, 0u};
        for (int t = ci + tid; t < NN * 8; t += 1024) d[t] = zz;
    }
    __syncthreads();

    const int q = lane >> 4;
    const int lofs = (lane & 15) << 3;
    const float4 w2v = *(const float4*)&W2[(lane & 15) << 2];
    const char* g2b = (const char*)g2;

    for (int k0 = kc0 + (w << 2); k0 < kc1; k0 += 64) {
        const int kq = k0 + q;
        const int kqc = kq < 511 ? kq : 511;
        int pk = (kq < kc1) ? (int)pcl[kqc] : 0;
        int mx = max(pk, __shfl_xor(pk, 16, 64));
        mx = max(mx, __shfl_xor(mx, 32, 64));
        const int nbu = __builtin_amdgcn_readfirstlane((mx + 3) >> 2);
        const uint4* l4 = (const uint4*)(nbr + kqc * MAXD);
        h4 acc0 = {}, acc1 = {};
        uint4 e0 = l4[0], e1 = l4[1];        // 2-deep rolling prefetch
        for (int g = 0; g < nbu; ++g) {
            uint4 en = l4[g + 2];            // harmless in-row over-read
            acc0 += *(const h4*)(g2b + (e0.x + lofs));
            acc1 += *(const h4*)(g2b + (e0.y + lofs));
            acc0 += *(const h4*)(g2b + (e0.z + lofs));
            acc1 += *(const h4*)(g2b + (e0.w + lofs));
            e0 = e1; e1 = en;
        }
        h4 acc = acc0 + acc1;
        const float dk = degl[kqc];
        float val = fmaxf(dk * (float)acc[0], 0.f) * w2v.x
                  + fmaxf(dk * (float)acc[1], 0.f) * w2v.y
                  + fmaxf(dk * (float)acc[2], 0.f) * w2v.z
                  + fmaxf(dk * (float)acc[3], 0.f) * w2v.w;
        #pragma unroll
        for (int mm = 1; mm <= 8; mm <<= 1) val += __shfl_xor(val, mm, 64);
        if ((lane & 15) == 0 && kq < kc1) ph[i * NN + kq] = dk * val;  // deg_k*hid
    }
}

// K3: supplement scatter (best config R19). s[i][j] = 0.5*deg_j*
// sum_{k in nbr(j), k<i} ph[i][k]; out[i][j] += s, out[j][i] += s
// (block i owns row i & col i -> race-free). Over-reads hit phl[r>=i] == 0.
__global__ __launch_bounds__(512) void supp(const unsigned* __restrict__ nbr,
                                            const unsigned char* __restrict__ pcntC,
                                            const float* __restrict__ ph,
                                            float* __restrict__ out) {
    __shared__ float phl[NN];
    const int i = 511 - (int)blockIdx.x;
    if (i < 1) return;
    const int tid = threadIdx.x;
    const int pc = (int)pcntC[tid * NN + i];         // strided byte gather (once)
    phl[tid] = (tid < i) ? ph[i * NN + tid] : 0.0f;  // ph already deg_k-scaled
    __syncthreads();
    if (tid < i) {
        const float d = rsqrtf((float)(pc > 0 ? pc : 1));
        const uint4* l4 = (const uint4*)(nbr + tid * MAXD);
        const int nb = (pc + 3) >> 2;
        float s = 0.f;
        for (int g = 0; g < nb; ++g) {
            uint4 qv = l4[g];   // over-read entries land on phl[r>=i] == 0
            s += phl[qv.x >> 7] + phl[qv.y >> 7] + phl[qv.z >> 7] + phl[qv.w >> 7];
        }
        s *= 0.5f * d;
        out[i * NN + tid] += s;
        out[tid * NN + i] += s;
    }
}

extern "C" void kernel_launch(void* const* d_in, const int* in_sizes, int n_in,
                              void* d_out, int out_size, void* d_ws, size_t ws_size,
                              hipStream_t stream) {
    const float* z   = (const float*)d_in[0];
    const float* adj = (const float*)d_in[1];
    const float* W1  = (const float*)d_in[2];
    const float* W2  = (const float*)d_in[3];
    float* out = (float*)d_out;

    char* wsp = (char*)d_ws;
    unsigned*       nbr   = (unsigned*)      (wsp + 0);
    _Float16*       g16   = (_Float16*)      (wsp + 196608);
    unsigned char*  pcntC = (unsigned char*) (wsp + 262144);
    float*          ph    = (float*)         (wsp + 524288);

    build_gemms<<<NN, 512, 0, stream>>>(adj, z, W1, nbr, pcntC, g16, out);
    hidk<<<dim3(3, NN), 1024, 0, stream>>>(nbr, pcntC, g16, W2, ph);
    supp<<<NN, 512, 0, stream>>>(nbr, pcntC, ph, out);
}